// Round 2
// baseline (179.315 us; speedup 1.0000x reference)
//
#include <hip/hip_runtime.h>
#include <cmath>

// Problem constants (from reference): B=32768, N=17, D=2, K=3, H=64
#define NBATCH 32768
#define NJOINT 17
#define OUT0_ELEMS (NBATCH * NJOINT * 15)          // out[B,N,3,5]
#define KJS_OFF    OUT0_ELEMS                      // k_js[B,N]
#define MASK_OFF   (KJS_OFF + NBATCH * NJOINT)     // mask[B,N,3]

typedef float v2f __attribute__((ext_vector_type(2)));

__device__ __forceinline__ v2f pkfma(v2f a, v2f b, v2f c) { return __builtin_elementwise_fma(a, b, c); }
__device__ __forceinline__ v2f pkmax(v2f a, v2f b)        { return __builtin_elementwise_max(a, b); }

__device__ __forceinline__ float sel3f(int i, float a, float b, float c) {
    return (i == 0) ? a : ((i == 1) ? b : c);
}

// Cold path: exact fp64 recompute of a 2->64->3 MLP's logits, only taken when
// the fp32 logits have a near-tie (< 1e-4 rel) that could flip argmax/argsort.
__device__ __noinline__ void mlp64_small(
    const float* __restrict__ W1a, const float* __restrict__ W1b,
    const float* __restrict__ b1,  const float* __restrict__ W2,
    const float* __restrict__ b2,
    double x0, double x1, double& l0, double& l1, double& l2)
{
    l0 = (double)b2[0]; l1 = (double)b2[1]; l2 = (double)b2[2];
    for (int h = 0; h < 64; ++h) {
        double hv = fma(x1, (double)W1b[h], fma(x0, (double)W1a[h], (double)b1[h]));
        hv = fmax(hv, 0.0);
        l0 = fma(hv, (double)W2[h * 3 + 0], l0);
        l1 = fma(hv, (double)W2[h * 3 + 1], l1);
        l2 = fma(hv, (double)W2[h * 3 + 2], l2);
    }
}

// Hot path: fp32 packed (v_pk_fma_f32) 2->64->3 MLP. Even h in .x, odd h in .y.
__device__ __forceinline__ void mlp32_small(
    const float* __restrict__ W1a, const float* __restrict__ W1b,
    const float* __restrict__ b1,  const float* __restrict__ W2,
    const float* __restrict__ b2,
    v2f vx0, v2f vx1, float& l0, float& l1, float& l2)
{
    v2f a0 = {0.f, 0.f}, a1 = {0.f, 0.f}, a2 = {0.f, 0.f};
    const v2f vzero = {0.f, 0.f};
    #pragma unroll 8
    for (int h = 0; h < 64; h += 2) {
        const v2f w1a = *reinterpret_cast<const v2f*>(W1a + h);   // 8B-aligned
        const v2f w1b = *reinterpret_cast<const v2f*>(W1b + h);
        const v2f bb  = *reinterpret_cast<const v2f*>(b1 + h);
        const v2f hv  = pkmax(pkfma(vx1, w1b, pkfma(vx0, w1a, bb)), vzero);
        v2f w20, w21, w22;                                        // strided gather (scalar loads)
        w20.x = W2[h * 3 + 0]; w20.y = W2[h * 3 + 3];
        w21.x = W2[h * 3 + 1]; w21.y = W2[h * 3 + 4];
        w22.x = W2[h * 3 + 2]; w22.y = W2[h * 3 + 5];
        a0 = pkfma(hv, w20, a0);
        a1 = pkfma(hv, w21, a1);
        a2 = pkfma(hv, w22, a2);
    }
    l0 = a0.x + a0.y + b2[0];
    l1 = a1.x + a1.y + b2[1];
    l2 = a2.x + a2.y + b2[2];
}

__global__ __launch_bounds__(256) void mdn_fused(
    const float* __restrict__ pred_pts,
    const float* __restrict__ kW1, const float* __restrict__ kb1,
    const float* __restrict__ kW2, const float* __restrict__ kb2,
    const float* __restrict__ wW1, const float* __restrict__ wb1,
    const float* __restrict__ wW2, const float* __restrict__ wb2,
    const float* __restrict__ bW1, const float* __restrict__ bb1,
    const float* __restrict__ bW2, const float* __restrict__ bb2,
    float* __restrict__ out)
{
    const int n = blockIdx.y;                 // wave-uniform -> scalar weight loads
    const int b = blockIdx.x * 256 + threadIdx.x;
    const int p = b * NJOINT + n;

    const float2 xv = *reinterpret_cast<const float2*>(pred_pts + 2 * p);
    const float x0f = xv.x, x1f = xv.y;
    const v2f vx0 = {x0f, x0f}, vx1 = {x1f, x1f};

    // ---------------- kMLP : 2 -> 64 -> 3, argmax+1 ------------------------
    const float* kW1a = kW1 + n * 128;
    const float* kW1b = kW1a + 64;
    const float* kb1p = kb1 + n * 64;
    const float* kW2p = kW2 + n * 192;
    const float* kb2p = kb2 + n * 3;
    float kf0, kf1, kf2;
    mlp32_small(kW1a, kW1b, kb1p, kW2p, kb2p, vx0, vx1, kf0, kf1, kf2);
    double kl0 = (double)kf0, kl1 = (double)kf1, kl2 = (double)kf2;
    {
        const float d01 = fabsf(kf0 - kf1), d02 = fabsf(kf0 - kf2), d12 = fabsf(kf1 - kf2);
        const float sc = fmaxf(fmaxf(fabsf(kf0), fabsf(kf1)), fabsf(kf2));
        if (fminf(fminf(d01, d02), d12) < 1e-4f * fmaxf(sc, 1.0f))
            mlp64_small(kW1a, kW1b, kb1p, kW2p, kb2p, (double)x0f, (double)x1f, kl0, kl1, kl2);
    }
    int kj = 0;  // first-occurrence argmax (jnp.argmax semantics)
    {
        double m = kl0;
        if (kl1 > m) { m = kl1; kj = 1; }
        if (kl2 > m) { kj = 2; }
    }

    // ---------------- wMLP : 2 -> 64 -> 3, softmax + argsort ---------------
    const float* wW1a = wW1 + n * 128;
    const float* wW1b = wW1a + 64;
    const float* wb1p = wb1 + n * 64;
    const float* wW2p = wW2 + n * 192;
    const float* wb2p = wb2 + n * 3;
    float wf0, wf1, wf2;
    mlp32_small(wW1a, wW1b, wb1p, wW2p, wb2p, vx0, vx1, wf0, wf1, wf2);
    double wl0 = (double)wf0, wl1 = (double)wf1, wl2 = (double)wf2;
    {
        const float d01 = fabsf(wf0 - wf1), d02 = fabsf(wf0 - wf2), d12 = fabsf(wf1 - wf2);
        const float sc = fmaxf(fmaxf(fabsf(wf0), fabsf(wf1)), fabsf(wf2));
        if (fminf(fminf(d01, d02), d12) < 1e-4f * fmaxf(sc, 1.0f))
            mlp64_small(wW1a, wW1b, wb1p, wW2p, wb2p, (double)x0f, (double)x1f, wl0, wl1, wl2);
    }
    // stable descending argsort of 3 (jnp.argsort(-w): ties -> lower index first)
    int i0 = 0;
    {
        double m = wl0;
        if (wl1 > m) { m = wl1; i0 = 1; }
        if (wl2 > m) { i0 = 2; }
    }
    const int ia = (i0 == 0) ? 1 : 0;
    const int ib = (i0 == 2) ? 1 : 2;
    const double wa = ia ? wl1 : wl0;
    const double wb = (ib == 1) ? wl1 : wl2;
    const int i1 = (wb > wa) ? ib : ia;
    const int i2 = (wb > wa) ? ia : ib;

    // softmax weights from fp32 logits (2% tolerance, error ~1e-6)
    const float mw = fmaxf(fmaxf(wf0, wf1), wf2);
    const float e0 = __expf(wf0 - mw);
    const float e1 = __expf(wf1 - mw);
    const float e2 = __expf(wf2 - mw);
    const float inv = 1.0f / (e0 + e1 + e2);
    const float p0 = e0 * inv, p1 = e1 * inv, p2 = e2 * inv;

    // ---------------- bMLP : 2 -> 128 -> 12 (packed fp32) ------------------
    v2f acc[6];
    {
        const float* W1a = bW1 + n * 256;
        const float* W1b = W1a + 128;
        const float* b1  = bb1 + n * 128;
        const float* W2  = bW2 + n * 1536;
        const float* b2  = bb2 + n * 12;
        #pragma unroll
        for (int j = 0; j < 6; ++j) acc[j] = *reinterpret_cast<const v2f*>(b2 + 2 * j);
        const v2f vzero = {0.f, 0.f};
        #pragma unroll 4
        for (int h = 0; h < 128; h += 2) {
            const v2f w1a = *reinterpret_cast<const v2f*>(W1a + h);
            const v2f w1b = *reinterpret_cast<const v2f*>(W1b + h);
            const v2f bb  = *reinterpret_cast<const v2f*>(b1 + h);
            const v2f hv2 = pkmax(pkfma(vx1, w1b, pkfma(vx0, w1a, bb)), vzero);
            const v2f vhx = {hv2.x, hv2.x};
            const v2f vhy = {hv2.y, hv2.y};
            const float* r0 = W2 + h * 12;
            #pragma unroll
            for (int j = 0; j < 6; ++j)
                acc[j] = pkfma(vhx, *reinterpret_cast<const v2f*>(r0 + 2 * j), acc[j]);
            const float* r1 = r0 + 12;
            #pragma unroll
            for (int j = 0; j < 6; ++j)
                acc[j] = pkfma(vhy, *reinterpret_cast<const v2f*>(r1 + 2 * j), acc[j]);
        }
    }
    float af[12];
    #pragma unroll
    for (int j = 0; j < 6; ++j) { af[2 * j] = acc[j].x; af[2 * j + 1] = acc[j].y; }

    // ---------------- epilogue: gather by sort order, write ----------------
    float r[15];
    r[0]  = p0; r[5] = p1; r[10] = p2;

    r[1]  = sel3f(i0, af[0], af[4], af[8]);
    r[2]  = sel3f(i0, af[1], af[5], af[9]);
    r[3]  = __expf(sel3f(i0, af[2], af[6], af[10]));
    r[4]  = __expf(sel3f(i0, af[3], af[7], af[11]));

    r[6]  = sel3f(i1, af[0], af[4], af[8]);
    r[7]  = sel3f(i1, af[1], af[5], af[9]);
    r[8]  = __expf(sel3f(i1, af[2], af[6], af[10]));
    r[9]  = __expf(sel3f(i1, af[3], af[7], af[11]));

    r[11] = sel3f(i2, af[0], af[4], af[8]);
    r[12] = sel3f(i2, af[1], af[5], af[9]);
    r[13] = __expf(sel3f(i2, af[2], af[6], af[10]));
    r[14] = __expf(sel3f(i2, af[3], af[7], af[11]));

    float* o = out + (size_t)p * 15;
    #pragma unroll
    for (int i = 0; i < 15; ++i) o[i] = r[i];

    out[KJS_OFF + p] = (float)(kj + 1);

    float* mk = out + MASK_OFF + (size_t)p * 3;
    mk[0] = 1.0f;
    mk[1] = (kj >= 1) ? 1.0f : 0.0f;
    mk[2] = (kj >= 2) ? 1.0f : 0.0f;
}

extern "C" void kernel_launch(void* const* d_in, const int* in_sizes, int n_in,
                              void* d_out, int out_size, void* d_ws, size_t ws_size,
                              hipStream_t stream) {
    (void)in_sizes; (void)n_in; (void)d_ws; (void)ws_size; (void)out_size;
    dim3 grid(NBATCH / 256, NJOINT);
    mdn_fused<<<grid, 256, 0, stream>>>(
        (const float*)d_in[0],
        (const float*)d_in[1], (const float*)d_in[2],
        (const float*)d_in[3], (const float*)d_in[4],
        (const float*)d_in[5], (const float*)d_in[6],
        (const float*)d_in[7], (const float*)d_in[8],
        (const float*)d_in[9], (const float*)d_in[10],
        (const float*)d_in[11], (const float*)d_in[12],
        (float*)d_out);
}